// Round 7
// baseline (292.612 us; speedup 1.0000x reference)
//
#include <hip/hip_runtime.h>
#include <hip/hip_bf16.h>

// GAT layer: xt = x@W; alpha = segment_softmax(leakyrelu(asrc[src]+adst[dst]));
// out = relu(mean_h(segment_sum(alpha*xt[src])) + bias)
// N=50000, F_IN=116, H=8, C=32, E=800000 (+N self loops)
//
// v7: alphas fused into gemm via the staged xs tile + transposed wsh in LDS
//     (alphas_k eliminated); gemm 16 rows/wave with explicit register
//     double-buffer of W (v6's VGPR=44 showed no SW pipelining -> 36% VALU);
//     init merged (zero + wsh precompute); scan2 fused into scan1 via
//     atomic-ticket finisher block. 9 launches -> 6.

#define F_IN 116
#define HC 256     // H*C
#define NHEAD 8
#define CDIM 32

typedef unsigned int uint32;

__device__ __forceinline__ unsigned short f2bf(float f) {
    uint32 u = __float_as_uint(f);
    u = (u + 0x7FFF + ((u >> 16) & 1)) >> 16;   // round-nearest-even
    return (unsigned short)u;
}

// ------- init: zero cnt+done, precompute wshT[o][k] = sum_c W[k,(o&7)*32+c]*att[o][c] -------
__global__ void init_k(int* __restrict__ cnt, int nzero,
                       const float* __restrict__ W,
                       const float* __restrict__ att_s,
                       const float* __restrict__ att_d,
                       float* __restrict__ wshT, int nzb) {
    if ((int)blockIdx.x < nzb) {
        int i = blockIdx.x * 256 + threadIdx.x;
        if (i < nzero) cnt[i] = 0;
    } else {
        int idx = (blockIdx.x - nzb) * 256 + threadIdx.x;
        if (idx < 16 * F_IN) {
            int o = idx / F_IN, k = idx - o * F_IN;
            int h = o & 7;
            const float* a = ((o < 8) ? att_s : att_d) + h * CDIM;
            const float* Wp = W + k * HC + h * CDIM;
            float s = 0.f;
#pragma unroll
            for (int c = 0; c < CDIM; ++c) s = fmaf(Wp[c], a[c], s);
            wshT[o * F_IN + k] = s;
        }
    }
}

// ------- GEMM + fused alphas -------
// 256 threads = 4 waves, 64 rows/block, wave w rows [w*16, w*16+16).
// W loads double-buffered in registers. Epilogue: 1024 (row,o) alpha dot-tasks
// from LDS (xs row float4 x wsT row float4).
__global__ __launch_bounds__(256, 4) void gemm_xt(const float* __restrict__ x,
                                                  const float* __restrict__ W,
                                                  const float* __restrict__ wshT,
                                                  unsigned short* __restrict__ xth,
                                                  float* __restrict__ asrc,
                                                  float* __restrict__ adst, int N) {
    __shared__ float xs[64 * F_IN];      // 29696 B
    __shared__ float ws[16 * F_IN];      // 7424 B
    const int t = threadIdx.x;
    const int row0 = blockIdx.x * 64;
    const int nrows = (N - row0 < 64) ? (N - row0) : 64;
    const int tot = nrows * F_IN;
    for (int i = t; i < tot; i += 256) xs[i] = x[(size_t)row0 * F_IN + i];
    for (int i = t; i < 16 * F_IN; i += 256) ws[i] = wshT[i];
    __syncthreads();

    const int w = t >> 6;
    const int lane = t & 63;
    const int r0 = w * 16;

    float acc[16][4];
#pragma unroll
    for (int r = 0; r < 16; ++r)
#pragma unroll
        for (int j = 0; j < 4; ++j) acc[r][j] = 0.f;

    float cw[4][4];
#pragma unroll
    for (int j = 0; j < 4; ++j) {
        const float* Wk = W + lane + 64 * j;
        cw[0][j] = Wk[0];
        cw[1][j] = Wk[HC];
        cw[2][j] = Wk[2 * HC];
        cw[3][j] = Wk[3 * HC];
    }

    for (int k4 = 0; k4 < F_IN / 4; ++k4) {
        // prefetch next k-slab of W into registers
        float nw[4][4];
        const int kn = (k4 < F_IN / 4 - 1) ? (k4 + 1) * 4 : k4 * 4;
#pragma unroll
        for (int j = 0; j < 4; ++j) {
            const float* Wk = W + kn * HC + lane + 64 * j;
            nw[0][j] = Wk[0];
            nw[1][j] = Wk[HC];
            nw[2][j] = Wk[2 * HC];
            nw[3][j] = Wk[3 * HC];
        }
        const int k = k4 * 4;
#pragma unroll
        for (int r = 0; r < 16; ++r) {
            float4 xv = *(const float4*)&xs[(r0 + r) * F_IN + k];
#pragma unroll
            for (int j = 0; j < 4; ++j)
                acc[r][j] = fmaf(xv.x, cw[0][j],
                            fmaf(xv.y, cw[1][j],
                            fmaf(xv.z, cw[2][j],
                            fmaf(xv.w, cw[3][j], acc[r][j]))));
        }
#pragma unroll
        for (int a = 0; a < 4; ++a)
#pragma unroll
            for (int j = 0; j < 4; ++j) cw[a][j] = nw[a][j];
    }

#pragma unroll
    for (int r = 0; r < 16; ++r) {
        const int row = row0 + r0 + r;
        if (row < N) {
#pragma unroll
            for (int j = 0; j < 4; ++j)
                xth[(size_t)row * HC + lane + 64 * j] = f2bf(acc[r][j]);
        }
    }

    // fused alphas: 1024 tasks, 4 per thread. task tid: row=tid>>4, o=tid&15.
#pragma unroll
    for (int q = 0; q < 4; ++q) {
        const int tid = q * 256 + t;
        const int row = tid >> 4;
        const int o = tid & 15;
        const int rg = row0 + row;
        const float4* xr = (const float4*)(xs + row * F_IN);   // 464B rows: 16B-aligned
        const float4* wr = (const float4*)(ws + o * F_IN);
        float s = 0.f;
#pragma unroll
        for (int k = 0; k < F_IN / 4; ++k) {
            float4 a = xr[k], b = wr[k];
            s = fmaf(a.x, b.x, fmaf(a.y, b.y, fmaf(a.z, b.z, fmaf(a.w, b.w, s))));
        }
        if (rg < N) {
            if (o < 8) asrc[rg * NHEAD + o] = s;
            else       adst[rg * NHEAD + o - 8] = s;
        }
    }
}

// ---------------- in-degree histogram + per-edge rank ----------------
__global__ void hist_k(const int* __restrict__ dst, int* __restrict__ cnt,
                       int* __restrict__ rank, int E) {
    int e = blockIdx.x * 256 + threadIdx.x;
    if (e < E) rank[e] = atomicAdd(&cnt[dst[e]], 1);
}

// ------- scan (local prefix + block sums; ticket-fused block-sum prefix) -------
__global__ __launch_bounds__(256) void scan_k(const int* __restrict__ cnt,
                                              int* __restrict__ offs,
                                              int* __restrict__ bsum,
                                              int* __restrict__ done, int N, int nb) {
    __shared__ int ts[256];
    const int t = threadIdx.x;
    const int base = blockIdx.x * 1024 + t * 4;
    int v[4];
    int s = 0;
#pragma unroll
    for (int j = 0; j < 4; ++j) {
        v[j] = (base + j < N) ? cnt[base + j] : 0;
        s += v[j];
    }
    ts[t] = s;
    __syncthreads();
    for (int off = 1; off < 256; off <<= 1) {
        int u = (t >= off) ? ts[t - off] : 0;
        __syncthreads();
        ts[t] += u;
        __syncthreads();
    }
    int run = t ? ts[t - 1] : 0;
#pragma unroll
    for (int j = 0; j < 4; ++j) {
        if (base + j <= N) offs[base + j] = run;   // include offs[N]
        run += v[j];
    }
    if (t == 255) {
        bsum[blockIdx.x] = ts[255];
        __threadfence();
    }
    __syncthreads();
    if (t == 0) {
        if (atomicAdd(done, 1) == nb - 1) {        // last block: prefix the block sums
            __threadfence();
            volatile int* vb = bsum;
            int acc = 0;
            for (int b = 0; b < nb; ++b) {
                int val = vb[b];
                vb[b] = acc;
                acc += val;
            }
            __threadfence();
        }
    }
}

// ---------------- CSR scatter, no atomics ----------------
__global__ void scatter_k(const int* __restrict__ src, const int* __restrict__ dst,
                          const int* __restrict__ rank,
                          const int* __restrict__ offs, const int* __restrict__ bsum,
                          int* __restrict__ csr, int E) {
    int e = blockIdx.x * 256 + threadIdx.x;
    if (e >= E) return;
    int d = dst[e];
    int p = offs[d] + bsum[d >> 10] + rank[e];
    csr[p] = src[e];
}

// ---------------- aggregate: one WAVE per destination node ----------------
__global__ __launch_bounds__(256) void aggregate_k(const unsigned short* __restrict__ xth,
                                                   const float* __restrict__ asrc,
                                                   const float* __restrict__ adst,
                                                   const int* __restrict__ offs,
                                                   const int* __restrict__ bsum,
                                                   const int* __restrict__ csr,
                                                   const float* __restrict__ bias,
                                                   float* __restrict__ out, int N) {
    const int t = threadIdx.x;
    const int l = t & 63;
    const int n = blockIdx.x * 4 + (t >> 6);
    if (n >= N) return;

    const int h_f = l >> 3;          // head for fma/accumulation
    const int h_w = l & 7;           // head for weight compute
    const int e_w = l >> 3;          // chunk-local edge for weight compute

    const int beg = offs[n] + bsum[n >> 10];
    const int d = offs[n + 1] + bsum[(n + 1) >> 10] - beg;

    const float adst_hw = adst[n * NHEAD + h_w];

    // self-loop
    float zs = asrc[n * NHEAD + h_f] + adst[n * NHEAD + h_f];
    zs = (zs > 0.f) ? zs : 0.2f * zs;
    const float wself = __expf(zs);

    uint2 sv = ((const uint2*)(xth + (size_t)n * HC))[l];
    float a0 = wself * __uint_as_float(sv.x << 16);
    float a1 = wself * __uint_as_float(sv.x & 0xFFFF0000u);
    float a2 = wself * __uint_as_float(sv.y << 16);
    float a3 = wself * __uint_as_float(sv.y & 0xFFFF0000u);
    float wsum = wself;

    const int nfull = d >> 3;
    const int rem = d & 7;
    int pos = beg;
    for (int cch = 0; cch < nfull; ++cch, pos += 8) {
        int s_w = csr[pos + e_w];
        float z = asrc[s_w * NHEAD + h_w] + adst_hw;
        z = (z > 0.f) ? z : 0.2f * z;
        float w_reg = __expf(z);
#pragma unroll
        for (int e = 0; e < 8; ++e) {
            int s = __shfl(s_w, e << 3, 64);
            float w = __shfl(w_reg, (e << 3) + h_f, 64);
            uint2 v = ((const uint2*)(xth + (size_t)s * HC))[l];
            a0 = fmaf(w, __uint_as_float(v.x << 16), a0);
            a1 = fmaf(w, __uint_as_float(v.x & 0xFFFF0000u), a1);
            a2 = fmaf(w, __uint_as_float(v.y << 16), a2);
            a3 = fmaf(w, __uint_as_float(v.y & 0xFFFF0000u), a3);
            wsum += w;
        }
    }
    if (rem) {
        int s_w = (e_w < rem) ? csr[pos + e_w] : n;
        float z = asrc[s_w * NHEAD + h_w] + adst_hw;
        z = (z > 0.f) ? z : 0.2f * z;
        float w_reg = __expf(z);
        for (int e = 0; e < rem; ++e) {
            int s = __shfl(s_w, e << 3, 64);
            float w = __shfl(w_reg, (e << 3) + h_f, 64);
            uint2 v = ((const uint2*)(xth + (size_t)s * HC))[l];
            a0 = fmaf(w, __uint_as_float(v.x << 16), a0);
            a1 = fmaf(w, __uint_as_float(v.x & 0xFFFF0000u), a1);
            a2 = fmaf(w, __uint_as_float(v.y << 16), a2);
            a3 = fmaf(w, __uint_as_float(v.y & 0xFFFF0000u), a3);
            wsum += w;
        }
    }

    const float inv = 1.f / (wsum + 1e-16f);
    a0 *= inv; a1 *= inv; a2 *= inv; a3 *= inv;

    // reduce over heads
#pragma unroll
    for (int o = 8; o <= 32; o <<= 1) {
        a0 += __shfl_xor(a0, o, 64);
        a1 += __shfl_xor(a1, o, 64);
        a2 += __shfl_xor(a2, o, 64);
        a3 += __shfl_xor(a3, o, 64);
    }

    if (l < 8) {
        const float* bp = bias + 4 * l;
        float4 r;
        r.x = fmaxf(a0 * 0.125f + bp[0], 0.f);
        r.y = fmaxf(a1 * 0.125f + bp[1], 0.f);
        r.z = fmaxf(a2 * 0.125f + bp[2], 0.f);
        r.w = fmaxf(a3 * 0.125f + bp[3], 0.f);
        *(float4*)&out[(size_t)n * CDIM + 4 * l] = r;
    }
}

extern "C" void kernel_launch(void* const* d_in, const int* in_sizes, int n_in,
                              void* d_out, int out_size, void* d_ws, size_t ws_size,
                              hipStream_t stream) {
    const float* x     = (const float*)d_in[0];
    const int*   ei    = (const int*)d_in[1];      // [2,E] int32: row0=src, row1=dst
    const float* W     = (const float*)d_in[2];
    const float* att_s = (const float*)d_in[3];
    const float* att_d = (const float*)d_in[4];
    const float* bias  = (const float*)d_in[5];
    float* out = (float*)d_out;

    const int N = in_sizes[0] / F_IN;    // 50000
    const int E = in_sizes[1] / 2;       // 800000

    // workspace layout (16B-aligned slices; N%4==0)
    unsigned short* xth = (unsigned short*)d_ws;          // 256N bf16
    float* asrc = (float*)(xth + (size_t)N * HC);         // 8N f32
    float* adst = asrc + (size_t)N * NHEAD;               // 8N
    float* wsh  = adst + (size_t)N * NHEAD;               // 16*116
    int*   offs = (int*)(wsh + 16 * F_IN);                // N+8
    int*   bsum = offs + (N + 8);                         // 64
    int*   cnt  = bsum + 64;                              // N
    int*   done = cnt + N;                                // 1 (+3 pad)
    int*   rank = done + 4;                               // E
    int*   csr  = rank + E;                               // E

    const int nb = (N + 1 + 1023) / 1024;                 // scan blocks (covers offs[N])
    const int nzero = N + 1;                              // cnt + done (contiguous)
    const int nzb = (nzero + 255) / 256;

    init_k<<<nzb + 8, 256, 0, stream>>>(cnt, nzero, W, att_s, att_d, wsh, nzb);
    gemm_xt<<<(N + 63) / 64, 256, 0, stream>>>(x, W, wsh, xth, asrc, adst, N);
    hist_k<<<(E + 255) / 256, 256, 0, stream>>>(ei + E, cnt, rank, E);
    scan_k<<<nb, 256, 0, stream>>>(cnt, offs, bsum, done, N, nb);
    scatter_k<<<(E + 255) / 256, 256, 0, stream>>>(ei, ei + E, rank, offs, bsum, csr, E);
    aggregate_k<<<(N + 3) / 4, 256, 0, stream>>>(xth, asrc, adst, offs, bsum, csr, bias, out, N);
}

// Round 8
// 265.008 us; speedup vs baseline: 1.1042x; 1.1042x over previous
//
#include <hip/hip_runtime.h>
#include <hip/hip_bf16.h>

// GAT layer: xt = x@W; alpha = segment_softmax(leakyrelu(asrc[src]+adst[dst]));
// out = relu(mean_h(segment_sum(alpha*xt[src])) + bias)
// N=50000, F_IN=116, H=8, C=32, E=800000 (+N self loops)
//
// v8: GEMM on v_mfma_f32_16x16x32_bf16 (68us fp32-vector -> target ~25us).
//     x cast to bf16 xb[N,128] inside alphas_k (which streams x anyway; alphas
//     stay f32-exact). W pre-cast/transposed to WbT[256,128] bf16 in init_k,
//     staged to LDS with +8/row pad (2-way bank aliasing = free).
//     Frag maps (m89/m120-verified): A[m=lane&15][k=quad*8+j], B dual,
//     C/D col=lane&15,row=quad*4+reg. v7's gemm prefetch/epilogue reverted
//     (grid-limited; it regressed 68->77).

#define F_IN 116
#define HC 256     // H*C
#define NHEAD 8
#define CDIM 32
#define KP 128         // K padded to 4 MFMA k-steps
#define ROWS_PB 48     // gemm rows per block
#define NPAD 50016     // xb row allocation (covers tail tiles)

typedef unsigned int uint32;
typedef short short8 __attribute__((ext_vector_type(8)));
typedef float f32x4 __attribute__((ext_vector_type(4)));

__device__ __forceinline__ unsigned short f2bf(float f) {
    uint32 u = __float_as_uint(f);
    u = (u + 0x7FFF + ((u >> 16) & 1)) >> 16;   // round-nearest-even
    return (unsigned short)u;
}

// ------- init: zero cnt+done; wsh[k*16+o]; WbT[n*128+k] = bf16(W[k][n]) -------
__global__ void init_k(int* __restrict__ cnt, int nzero,
                       const float* __restrict__ W,
                       const float* __restrict__ att_s,
                       const float* __restrict__ att_d,
                       float* __restrict__ wsh,
                       unsigned short* __restrict__ WbT, int nzb) {
    const int b = blockIdx.x;
    if (b < nzb) {
        int i = b * 256 + threadIdx.x;
        if (i < nzero) cnt[i] = 0;
    } else if (b < nzb + 8) {
        int idx = (b - nzb) * 256 + threadIdx.x;
        if (idx < F_IN * 16) {
            int k = idx >> 4, o = idx & 15;
            const float* a = ((o < 8) ? att_s : att_d) + (o & 7) * CDIM;
            const float* Wp = W + k * HC + (o & 7) * CDIM;
            float s = 0.f;
#pragma unroll
            for (int c = 0; c < CDIM; ++c) s = fmaf(Wp[c], a[c], s);
            wsh[idx] = s;
        }
    } else {
        int idx = (b - nzb - 8) * 256 + threadIdx.x;   // 0..32767
        int n = idx >> 7, k = idx & 127;
        WbT[n * KP + k] = (k < F_IN) ? f2bf(W[k * HC + n]) : (unsigned short)0;
    }
}

// ------- alphas (f32-exact) + xb bf16 cast -------
// 4 waves/block, one row per wave. Lane l: alpha task o=l&15, k-part l>>4.
__global__ __launch_bounds__(256) void alphas_k(const float* __restrict__ x,
                                                const float* __restrict__ wsh,
                                                float* __restrict__ asrc,
                                                float* __restrict__ adst,
                                                unsigned short* __restrict__ xb, int N) {
    __shared__ float ws[F_IN * 16];
    const int t = threadIdx.x;
    for (int i = t; i < F_IN * 16; i += 256) ws[i] = wsh[i];
    __syncthreads();

    const int row = blockIdx.x * 4 + (t >> 6);
    if (row >= N) return;
    const int l = t & 63;
    const float* xr0 = x + (size_t)row * F_IN;

    // bf16 cast + zero-pad to 128
    float v0 = (l < F_IN) ? xr0[l] : 0.f;
    float v1 = (l + 64 < F_IN) ? xr0[l + 64] : 0.f;
    xb[(size_t)row * KP + l] = f2bf(v0);
    xb[(size_t)row * KP + l + 64] = f2bf(v1);

    const int o = l & 15;
    const int part = l >> 4;                 // 4 parts x 29 k
    const float* xr = xr0 + part * 29;
    float s = 0.f;
#pragma unroll
    for (int i = 0; i < 29; ++i) s = fmaf(xr[i], ws[(part * 29 + i) * 16 + o], s);
    s += __shfl_xor(s, 16, 64);
    s += __shfl_xor(s, 32, 64);
    if (l < 16) {
        if (o < 8) asrc[row * NHEAD + o] = s;
        else       adst[row * NHEAD + o - 8] = s;
    }
}

// ------- GEMM via MFMA: xth[N,256](bf16) = bf16(xb @ WbT^T) -------
// 4 waves: wave w covers cols [w*64, w*64+64); block covers 48 rows.
// Per wave: 3 row-tiles x 4 col-tiles of 16x16, K = 4 steps of 32.
__global__ __launch_bounds__(256) void gemm_xt(const unsigned short* __restrict__ xb,
                                               const unsigned short* __restrict__ WbT,
                                               unsigned short* __restrict__ xth, int N) {
    __shared__ unsigned short wsT[256 * 136];   // 69632 B, +8/row pad
    const int t = threadIdx.x;
    {   // stage WbT: thread t = col n, 16 x 16B chunks
        const short8* src = (const short8*)(WbT + t * KP);
#pragma unroll
        for (int c = 0; c < 16; ++c)
            *(short8*)&wsT[t * 136 + c * 8] = src[c];
    }
    __syncthreads();

    const int w = t >> 6, l = t & 63;
    const int q = l >> 4, m = l & 15;
    const int row0 = blockIdx.x * ROWS_PB;
    const int ncol0 = w * 64;

    f32x4 acc[3][4];
#pragma unroll
    for (int rt = 0; rt < 3; ++rt)
#pragma unroll
        for (int nt = 0; nt < 4; ++nt) acc[rt][nt] = f32x4{0.f, 0.f, 0.f, 0.f};

#pragma unroll
    for (int ks = 0; ks < 4; ++ks) {
        short8 a[3];
#pragma unroll
        for (int rt = 0; rt < 3; ++rt)
            a[rt] = *(const short8*)&xb[(size_t)(row0 + rt * 16 + m) * KP + ks * 32 + q * 8];
#pragma unroll
        for (int nt = 0; nt < 4; ++nt) {
            short8 bfrag = *(const short8*)&wsT[(ncol0 + nt * 16 + m) * 136 + ks * 32 + q * 8];
#pragma unroll
            for (int rt = 0; rt < 3; ++rt)
                acc[rt][nt] = __builtin_amdgcn_mfma_f32_16x16x32_bf16(a[rt], bfrag, acc[rt][nt], 0, 0, 0);
        }
    }

#pragma unroll
    for (int rt = 0; rt < 3; ++rt)
#pragma unroll
        for (int r = 0; r < 4; ++r) {
            const int row = row0 + rt * 16 + q * 4 + r;
            if (row < N) {
#pragma unroll
                for (int nt = 0; nt < 4; ++nt)
                    xth[(size_t)row * HC + ncol0 + nt * 16 + m] = f2bf(acc[rt][nt][r]);
            }
        }
}

// ---------------- in-degree histogram + per-edge rank ----------------
__global__ void hist_k(const int* __restrict__ dst, int* __restrict__ cnt,
                       int* __restrict__ rank, int E) {
    int e = blockIdx.x * 256 + threadIdx.x;
    if (e < E) rank[e] = atomicAdd(&cnt[dst[e]], 1);
}

// ------- scan (local prefix + block sums; ticket-fused block-sum prefix) -------
__global__ __launch_bounds__(256) void scan_k(const int* __restrict__ cnt,
                                              int* __restrict__ offs,
                                              int* __restrict__ bsum,
                                              int* __restrict__ done, int N, int nb) {
    __shared__ int ts[256];
    const int t = threadIdx.x;
    const int base = blockIdx.x * 1024 + t * 4;
    int v[4];
    int s = 0;
#pragma unroll
    for (int j = 0; j < 4; ++j) {
        v[j] = (base + j < N) ? cnt[base + j] : 0;
        s += v[j];
    }
    ts[t] = s;
    __syncthreads();
    for (int off = 1; off < 256; off <<= 1) {
        int u = (t >= off) ? ts[t - off] : 0;
        __syncthreads();
        ts[t] += u;
        __syncthreads();
    }
    int run = t ? ts[t - 1] : 0;
#pragma unroll
    for (int j = 0; j < 4; ++j) {
        if (base + j <= N) offs[base + j] = run;   // include offs[N]
        run += v[j];
    }
    if (t == 255) {
        bsum[blockIdx.x] = ts[255];
        __threadfence();
    }
    __syncthreads();
    if (t == 0) {
        if (atomicAdd(done, 1) == nb - 1) {        // last block prefixes block sums
            __threadfence();
            volatile int* vb = bsum;
            int acc = 0;
            for (int b = 0; b < nb; ++b) {
                int val = vb[b];
                vb[b] = acc;
                acc += val;
            }
            __threadfence();
        }
    }
}

// ---------------- CSR scatter, no atomics ----------------
__global__ void scatter_k(const int* __restrict__ src, const int* __restrict__ dst,
                          const int* __restrict__ rank,
                          const int* __restrict__ offs, const int* __restrict__ bsum,
                          int* __restrict__ csr, int E) {
    int e = blockIdx.x * 256 + threadIdx.x;
    if (e >= E) return;
    int d = dst[e];
    int p = offs[d] + bsum[d >> 10] + rank[e];
    csr[p] = src[e];
}

// ---------------- aggregate: one WAVE per destination node ----------------
__global__ __launch_bounds__(256) void aggregate_k(const unsigned short* __restrict__ xth,
                                                   const float* __restrict__ asrc,
                                                   const float* __restrict__ adst,
                                                   const int* __restrict__ offs,
                                                   const int* __restrict__ bsum,
                                                   const int* __restrict__ csr,
                                                   const float* __restrict__ bias,
                                                   float* __restrict__ out, int N) {
    const int t = threadIdx.x;
    const int l = t & 63;
    const int n = blockIdx.x * 4 + (t >> 6);
    if (n >= N) return;

    const int h_f = l >> 3;          // head for fma/accumulation
    const int h_w = l & 7;           // head for weight compute
    const int e_w = l >> 3;          // chunk-local edge for weight compute

    const int beg = offs[n] + bsum[n >> 10];
    const int d = offs[n + 1] + bsum[(n + 1) >> 10] - beg;

    const float adst_hw = adst[n * NHEAD + h_w];

    float zs = asrc[n * NHEAD + h_f] + adst[n * NHEAD + h_f];
    zs = (zs > 0.f) ? zs : 0.2f * zs;
    const float wself = __expf(zs);

    uint2 sv = ((const uint2*)(xth + (size_t)n * HC))[l];
    float a0 = wself * __uint_as_float(sv.x << 16);
    float a1 = wself * __uint_as_float(sv.x & 0xFFFF0000u);
    float a2 = wself * __uint_as_float(sv.y << 16);
    float a3 = wself * __uint_as_float(sv.y & 0xFFFF0000u);
    float wsum = wself;

    const int nfull = d >> 3;
    const int rem = d & 7;
    int pos = beg;
    for (int cch = 0; cch < nfull; ++cch, pos += 8) {
        int s_w = csr[pos + e_w];
        float z = asrc[s_w * NHEAD + h_w] + adst_hw;
        z = (z > 0.f) ? z : 0.2f * z;
        float w_reg = __expf(z);
#pragma unroll
        for (int e = 0; e < 8; ++e) {
            int s = __shfl(s_w, e << 3, 64);
            float w = __shfl(w_reg, (e << 3) + h_f, 64);
            uint2 v = ((const uint2*)(xth + (size_t)s * HC))[l];
            a0 = fmaf(w, __uint_as_float(v.x << 16), a0);
            a1 = fmaf(w, __uint_as_float(v.x & 0xFFFF0000u), a1);
            a2 = fmaf(w, __uint_as_float(v.y << 16), a2);
            a3 = fmaf(w, __uint_as_float(v.y & 0xFFFF0000u), a3);
            wsum += w;
        }
    }
    if (rem) {
        int s_w = (e_w < rem) ? csr[pos + e_w] : n;
        float z = asrc[s_w * NHEAD + h_w] + adst_hw;
        z = (z > 0.f) ? z : 0.2f * z;
        float w_reg = __expf(z);
        for (int e = 0; e < rem; ++e) {
            int s = __shfl(s_w, e << 3, 64);
            float w = __shfl(w_reg, (e << 3) + h_f, 64);
            uint2 v = ((const uint2*)(xth + (size_t)s * HC))[l];
            a0 = fmaf(w, __uint_as_float(v.x << 16), a0);
            a1 = fmaf(w, __uint_as_float(v.x & 0xFFFF0000u), a1);
            a2 = fmaf(w, __uint_as_float(v.y << 16), a2);
            a3 = fmaf(w, __uint_as_float(v.y & 0xFFFF0000u), a3);
            wsum += w;
        }
    }

    const float inv = 1.f / (wsum + 1e-16f);
    a0 *= inv; a1 *= inv; a2 *= inv; a3 *= inv;

#pragma unroll
    for (int o = 8; o <= 32; o <<= 1) {
        a0 += __shfl_xor(a0, o, 64);
        a1 += __shfl_xor(a1, o, 64);
        a2 += __shfl_xor(a2, o, 64);
        a3 += __shfl_xor(a3, o, 64);
    }

    if (l < 8) {
        const float* bp = bias + 4 * l;
        float4 r;
        r.x = fmaxf(a0 * 0.125f + bp[0], 0.f);
        r.y = fmaxf(a1 * 0.125f + bp[1], 0.f);
        r.z = fmaxf(a2 * 0.125f + bp[2], 0.f);
        r.w = fmaxf(a3 * 0.125f + bp[3], 0.f);
        *(float4*)&out[(size_t)n * CDIM + 4 * l] = r;
    }
}

extern "C" void kernel_launch(void* const* d_in, const int* in_sizes, int n_in,
                              void* d_out, int out_size, void* d_ws, size_t ws_size,
                              hipStream_t stream) {
    const float* x     = (const float*)d_in[0];
    const int*   ei    = (const int*)d_in[1];      // [2,E] int32: row0=src, row1=dst
    const float* W     = (const float*)d_in[2];
    const float* att_s = (const float*)d_in[3];
    const float* att_d = (const float*)d_in[4];
    const float* bias  = (const float*)d_in[5];
    float* out = (float*)d_out;

    const int N = in_sizes[0] / F_IN;    // 50000
    const int E = in_sizes[1] / 2;       // 800000

    // workspace layout (16B-aligned slices)
    unsigned short* xth = (unsigned short*)d_ws;          // 256N bf16
    unsigned short* xb  = xth + (size_t)N * HC;           // 128*NPAD bf16
    unsigned short* WbT = xb + (size_t)NPAD * KP;         // 256*128 bf16
    float* asrc = (float*)(WbT + 256 * KP);               // 8N f32
    float* adst = asrc + (size_t)N * NHEAD;               // 8N
    float* wsh  = adst + (size_t)N * NHEAD;               // 16*116
    int*   offs = (int*)(wsh + 16 * F_IN);                // N+8
    int*   bsum = offs + (N + 8);                         // 64
    int*   cnt  = bsum + 64;                              // N
    int*   done = cnt + N;                                // 4
    int*   rank = done + 4;                               // E
    int*   csr  = rank + E;                               // E

    const int nb = (N + 1 + 1023) / 1024;                 // scan blocks
    const int nzero = N + 4;                              // cnt + done
    const int nzb = (nzero + 255) / 256;

    init_k<<<nzb + 8 + 128, 256, 0, stream>>>(cnt, nzero, W, att_s, att_d, wsh, WbT, nzb);
    alphas_k<<<(N + 3) / 4, 256, 0, stream>>>(x, wsh, asrc, adst, xb, N);
    gemm_xt<<<(N + ROWS_PB - 1) / ROWS_PB, 256, 0, stream>>>(xb, WbT, xth, N);
    hist_k<<<(E + 255) / 256, 256, 0, stream>>>(ei + E, cnt, rank, E);
    scan_k<<<nb, 256, 0, stream>>>(cnt, offs, bsum, done, N, nb);
    scatter_k<<<(E + 255) / 256, 256, 0, stream>>>(ei, ei + E, rank, offs, bsum, csr, E);
    aggregate_k<<<(N + 3) / 4, 256, 0, stream>>>(xth, asrc, adst, offs, bsum, csr, bias, out, N);
}

// Round 9
// 241.959 us; speedup vs baseline: 1.2093x; 1.0953x over previous
//
#include <hip/hip_runtime.h>
#include <hip/hip_bf16.h>

// GAT layer: xt = x@W; alpha = segment_softmax(leakyrelu(asrc[src]+adst[dst]));
// out = relu(mean_h(segment_sum(alpha*xt[src])) + bias)
// N=50000, F_IN=116, H=8, C=32, E=800000 (+N self loops)
//
// v9: overlap via fusion (stream serializes separate launches):
//     fuse1 = alphas (N-part) || hist (E-part), 4:1 interleaved blocks;
//     fuse2 = MFMA gemm || scan. gemm drops LDS: B-frags (64KB WbT) live in
//     16 short8 regs/wave, loaded from L2-hot global — no barriers, 3 blk/CU.
//     aggregate (68us, FETCH 219MB = random-gather floor ~3.4TB/s) unchanged.

#define F_IN 116
#define HC 256     // H*C
#define NHEAD 8
#define CDIM 32
#define KP 128         // K padded to 4 MFMA k-steps
#define ROWS_PB 48     // gemm rows per block
#define NPAD 50016     // xb row allocation (covers tail tiles)

typedef unsigned int uint32;
typedef short short8 __attribute__((ext_vector_type(8)));
typedef float f32x4 __attribute__((ext_vector_type(4)));

__device__ __forceinline__ unsigned short f2bf(float f) {
    uint32 u = __float_as_uint(f);
    u = (u + 0x7FFF + ((u >> 16) & 1)) >> 16;   // round-nearest-even
    return (unsigned short)u;
}

// ------- init: zero cnt+done; wsh[k*16+o]; WbT[n*128+k] = bf16(W[k][n]) -------
__global__ void init_k(int* __restrict__ cnt, int nzero,
                       const float* __restrict__ W,
                       const float* __restrict__ att_s,
                       const float* __restrict__ att_d,
                       float* __restrict__ wsh,
                       unsigned short* __restrict__ WbT, int nzb) {
    const int b = blockIdx.x;
    if (b < nzb) {
        int i = b * 256 + threadIdx.x;
        if (i < nzero) cnt[i] = 0;
    } else if (b < nzb + 8) {
        int idx = (b - nzb) * 256 + threadIdx.x;
        if (idx < F_IN * 16) {
            int k = idx >> 4, o = idx & 15;
            const float* a = ((o < 8) ? att_s : att_d) + (o & 7) * CDIM;
            const float* Wp = W + k * HC + (o & 7) * CDIM;
            float s = 0.f;
#pragma unroll
            for (int c = 0; c < CDIM; ++c) s = fmaf(Wp[c], a[c], s);
            wsh[idx] = s;
        }
    } else {
        int idx = (b - nzb - 8) * 256 + threadIdx.x;   // 0..32767
        int n = idx >> 7, k = idx & 127;
        WbT[n * KP + k] = (k < F_IN) ? f2bf(W[k * HC + n]) : (unsigned short)0;
    }
}

// ------- fuse1: alphas+xb cast (blocks %5 != 4) || hist+rank (blocks %5 == 4) -------
__global__ __launch_bounds__(256) void fuse1_k(const float* __restrict__ x,
                                               const float* __restrict__ wsh,
                                               float* __restrict__ asrc,
                                               float* __restrict__ adst,
                                               unsigned short* __restrict__ xb, int N,
                                               const int* __restrict__ dst,
                                               int* __restrict__ cnt,
                                               int* __restrict__ rank, int E) {
    const int bid = blockIdx.x;
    const int t = threadIdx.x;
    if ((bid % 5) == 4) {
        // ---- hist part ----
        int e = (bid / 5) * 256 + t;
        if (e < E) rank[e] = atomicAdd(&cnt[dst[e]], 1);
        return;
    }
    // ---- alphas part ----
    const int ab = (bid / 5) * 4 + (bid % 5);
    __shared__ float ws[F_IN * 16];
    for (int i = t; i < F_IN * 16; i += 256) ws[i] = wsh[i];
    __syncthreads();

    const int row = ab * 4 + (t >> 6);
    if (row >= N) return;
    const int l = t & 63;
    const float* xr0 = x + (size_t)row * F_IN;

    // bf16 cast + zero-pad to 128
    float v0 = (l < F_IN) ? xr0[l] : 0.f;
    float v1 = (l + 64 < F_IN) ? xr0[l + 64] : 0.f;
    xb[(size_t)row * KP + l] = f2bf(v0);
    xb[(size_t)row * KP + l + 64] = f2bf(v1);

    const int o = l & 15;
    const int part = l >> 4;                 // 4 parts x 29 k
    const float* xr = xr0 + part * 29;
    float s = 0.f;
#pragma unroll
    for (int i = 0; i < 29; ++i) s = fmaf(xr[i], ws[(part * 29 + i) * 16 + o], s);
    s += __shfl_xor(s, 16, 64);
    s += __shfl_xor(s, 32, 64);
    if (l < 16) {
        if (o < 8) asrc[row * NHEAD + o] = s;
        else       adst[row * NHEAD + o - 8] = s;
    }
}

// ------- fuse2: MFMA gemm (blocks < Ggemm) || scan (blocks >= Ggemm) -------
// gemm: 4 waves = 4 col-strips of 64; 48 rows/block; B-frags in registers
// (16 x short8 from L2-hot WbT), no LDS, no barriers.
__global__ __launch_bounds__(256) void fuse2_k(const unsigned short* __restrict__ xb,
                                               const unsigned short* __restrict__ WbT,
                                               unsigned short* __restrict__ xth, int N,
                                               int Ggemm,
                                               const int* __restrict__ cnt,
                                               int* __restrict__ offs,
                                               int* __restrict__ bsum,
                                               int* __restrict__ done, int nb) {
    const int t = threadIdx.x;
    if ((int)blockIdx.x < Ggemm) {
        const int w = t >> 6, l = t & 63;
        const int q = l >> 4, m = l & 15;
        const int row0 = blockIdx.x * ROWS_PB;
        const int ncol0 = w * 64;

        // B fragments: [nt][ks], each 16B/lane
        short8 bfr[4][4];
#pragma unroll
        for (int nt = 0; nt < 4; ++nt)
#pragma unroll
            for (int ks = 0; ks < 4; ++ks)
                bfr[nt][ks] = *(const short8*)&WbT[(size_t)(ncol0 + nt * 16 + m) * KP + ks * 32 + q * 8];

        f32x4 acc[3][4];
#pragma unroll
        for (int rt = 0; rt < 3; ++rt)
#pragma unroll
            for (int nt = 0; nt < 4; ++nt) acc[rt][nt] = f32x4{0.f, 0.f, 0.f, 0.f};

#pragma unroll
        for (int ks = 0; ks < 4; ++ks) {
            short8 a[3];
#pragma unroll
            for (int rt = 0; rt < 3; ++rt)
                a[rt] = *(const short8*)&xb[(size_t)(row0 + rt * 16 + m) * KP + ks * 32 + q * 8];
#pragma unroll
            for (int nt = 0; nt < 4; ++nt)
#pragma unroll
                for (int rt = 0; rt < 3; ++rt)
                    acc[rt][nt] = __builtin_amdgcn_mfma_f32_16x16x32_bf16(a[rt], bfr[nt][ks], acc[rt][nt], 0, 0, 0);
        }

#pragma unroll
        for (int rt = 0; rt < 3; ++rt)
#pragma unroll
            for (int r = 0; r < 4; ++r) {
                const int row = row0 + rt * 16 + q * 4 + r;
                if (row < N) {
#pragma unroll
                    for (int nt = 0; nt < 4; ++nt)
                        xth[(size_t)row * HC + ncol0 + nt * 16 + m] = f2bf(acc[rt][nt][r]);
                }
            }
        return;
    }

    // ---- scan part ----
    const int sb = blockIdx.x - Ggemm;
    __shared__ int ts[256];
    const int base = sb * 1024 + t * 4;
    int v[4];
    int s = 0;
#pragma unroll
    for (int j = 0; j < 4; ++j) {
        v[j] = (base + j < N) ? cnt[base + j] : 0;
        s += v[j];
    }
    ts[t] = s;
    __syncthreads();
    for (int off = 1; off < 256; off <<= 1) {
        int u = (t >= off) ? ts[t - off] : 0;
        __syncthreads();
        ts[t] += u;
        __syncthreads();
    }
    int run = t ? ts[t - 1] : 0;
#pragma unroll
    for (int j = 0; j < 4; ++j) {
        if (base + j <= N) offs[base + j] = run;   // include offs[N]
        run += v[j];
    }
    if (t == 255) {
        bsum[sb] = ts[255];
        __threadfence();
    }
    __syncthreads();
    if (t == 0) {
        if (atomicAdd(done, 1) == nb - 1) {        // last block prefixes block sums
            __threadfence();
            volatile int* vb = bsum;
            int acc = 0;
            for (int b = 0; b < nb; ++b) {
                int val = vb[b];
                vb[b] = acc;
                acc += val;
            }
            __threadfence();
        }
    }
}

// ---------------- CSR scatter, no atomics ----------------
__global__ void scatter_k(const int* __restrict__ src, const int* __restrict__ dst,
                          const int* __restrict__ rank,
                          const int* __restrict__ offs, const int* __restrict__ bsum,
                          int* __restrict__ csr, int E) {
    int e = blockIdx.x * 256 + threadIdx.x;
    if (e >= E) return;
    int d = dst[e];
    int p = offs[d] + bsum[d >> 10] + rank[e];
    csr[p] = src[e];
}

// ---------------- aggregate: one WAVE per destination node ----------------
__global__ __launch_bounds__(256) void aggregate_k(const unsigned short* __restrict__ xth,
                                                   const float* __restrict__ asrc,
                                                   const float* __restrict__ adst,
                                                   const int* __restrict__ offs,
                                                   const int* __restrict__ bsum,
                                                   const int* __restrict__ csr,
                                                   const float* __restrict__ bias,
                                                   float* __restrict__ out, int N) {
    const int t = threadIdx.x;
    const int l = t & 63;
    const int n = blockIdx.x * 4 + (t >> 6);
    if (n >= N) return;

    const int h_f = l >> 3;          // head for fma/accumulation
    const int h_w = l & 7;           // head for weight compute
    const int e_w = l >> 3;          // chunk-local edge for weight compute

    const int beg = offs[n] + bsum[n >> 10];
    const int d = offs[n + 1] + bsum[(n + 1) >> 10] - beg;

    const float adst_hw = adst[n * NHEAD + h_w];

    float zs = asrc[n * NHEAD + h_f] + adst[n * NHEAD + h_f];
    zs = (zs > 0.f) ? zs : 0.2f * zs;
    const float wself = __expf(zs);

    uint2 sv = ((const uint2*)(xth + (size_t)n * HC))[l];
    float a0 = wself * __uint_as_float(sv.x << 16);
    float a1 = wself * __uint_as_float(sv.x & 0xFFFF0000u);
    float a2 = wself * __uint_as_float(sv.y << 16);
    float a3 = wself * __uint_as_float(sv.y & 0xFFFF0000u);
    float wsum = wself;

    const int nfull = d >> 3;
    const int rem = d & 7;
    int pos = beg;
    for (int cch = 0; cch < nfull; ++cch, pos += 8) {
        int s_w = csr[pos + e_w];
        float z = asrc[s_w * NHEAD + h_w] + adst_hw;
        z = (z > 0.f) ? z : 0.2f * z;
        float w_reg = __expf(z);
#pragma unroll
        for (int e = 0; e < 8; ++e) {
            int s = __shfl(s_w, e << 3, 64);
            float w = __shfl(w_reg, (e << 3) + h_f, 64);
            uint2 v = ((const uint2*)(xth + (size_t)s * HC))[l];
            a0 = fmaf(w, __uint_as_float(v.x << 16), a0);
            a1 = fmaf(w, __uint_as_float(v.x & 0xFFFF0000u), a1);
            a2 = fmaf(w, __uint_as_float(v.y << 16), a2);
            a3 = fmaf(w, __uint_as_float(v.y & 0xFFFF0000u), a3);
            wsum += w;
        }
    }
    if (rem) {
        int s_w = (e_w < rem) ? csr[pos + e_w] : n;
        float z = asrc[s_w * NHEAD + h_w] + adst_hw;
        z = (z > 0.f) ? z : 0.2f * z;
        float w_reg = __expf(z);
        for (int e = 0; e < rem; ++e) {
            int s = __shfl(s_w, e << 3, 64);
            float w = __shfl(w_reg, (e << 3) + h_f, 64);
            uint2 v = ((const uint2*)(xth + (size_t)s * HC))[l];
            a0 = fmaf(w, __uint_as_float(v.x << 16), a0);
            a1 = fmaf(w, __uint_as_float(v.x & 0xFFFF0000u), a1);
            a2 = fmaf(w, __uint_as_float(v.y << 16), a2);
            a3 = fmaf(w, __uint_as_float(v.y & 0xFFFF0000u), a3);
            wsum += w;
        }
    }

    const float inv = 1.f / (wsum + 1e-16f);
    a0 *= inv; a1 *= inv; a2 *= inv; a3 *= inv;

#pragma unroll
    for (int o = 8; o <= 32; o <<= 1) {
        a0 += __shfl_xor(a0, o, 64);
        a1 += __shfl_xor(a1, o, 64);
        a2 += __shfl_xor(a2, o, 64);
        a3 += __shfl_xor(a3, o, 64);
    }

    if (l < 8) {
        const float* bp = bias + 4 * l;
        float4 r;
        r.x = fmaxf(a0 * 0.125f + bp[0], 0.f);
        r.y = fmaxf(a1 * 0.125f + bp[1], 0.f);
        r.z = fmaxf(a2 * 0.125f + bp[2], 0.f);
        r.w = fmaxf(a3 * 0.125f + bp[3], 0.f);
        *(float4*)&out[(size_t)n * CDIM + 4 * l] = r;
    }
}

extern "C" void kernel_launch(void* const* d_in, const int* in_sizes, int n_in,
                              void* d_out, int out_size, void* d_ws, size_t ws_size,
                              hipStream_t stream) {
    const float* x     = (const float*)d_in[0];
    const int*   ei    = (const int*)d_in[1];      // [2,E] int32: row0=src, row1=dst
    const float* W     = (const float*)d_in[2];
    const float* att_s = (const float*)d_in[3];
    const float* att_d = (const float*)d_in[4];
    const float* bias  = (const float*)d_in[5];
    float* out = (float*)d_out;

    const int N = in_sizes[0] / F_IN;    // 50000
    const int E = in_sizes[1] / 2;       // 800000

    // workspace layout (16B-aligned slices)
    unsigned short* xth = (unsigned short*)d_ws;          // 256N bf16
    unsigned short* xb  = xth + (size_t)N * HC;           // 128*NPAD bf16
    unsigned short* WbT = xb + (size_t)NPAD * KP;         // 256*128 bf16
    float* asrc = (float*)(WbT + 256 * KP);               // 8N f32
    float* adst = asrc + (size_t)N * NHEAD;               // 8N
    float* wsh  = adst + (size_t)N * NHEAD;               // 16*116
    int*   offs = (int*)(wsh + 16 * F_IN);                // N+8
    int*   bsum = offs + (N + 8);                         // 64
    int*   cnt  = bsum + 64;                              // N
    int*   done = cnt + N;                                // 4
    int*   rank = done + 4;                               // E
    int*   csr  = rank + E;                               // E

    const int nb = (N + 1 + 1023) / 1024;                 // scan blocks
    const int nzero = N + 4;                              // cnt + done
    const int nzb = (nzero + 255) / 256;
    const int Ggemm = (N + ROWS_PB - 1) / ROWS_PB;        // 1042
    const int nalpha = (N + 3) / 4;                       // 12500 (divisible by 4)
    const int nhist = (E + 255) / 256;                    // 3125 = nalpha/4 exactly

    init_k<<<nzb + 8 + 128, 256, 0, stream>>>(cnt, nzero, W, att_s, att_d, wsh, WbT, nzb);
    fuse1_k<<<nalpha + nhist, 256, 0, stream>>>(x, wsh, asrc, adst, xb, N,
                                                ei + E, cnt, rank, E);
    fuse2_k<<<Ggemm + nb, 256, 0, stream>>>(xb, WbT, xth, N, Ggemm,
                                            cnt, offs, bsum, done, nb);
    scatter_k<<<(E + 255) / 256, 256, 0, stream>>>(ei, ei + E, rank, offs, bsum, csr, E);
    aggregate_k<<<(N + 3) / 4, 256, 0, stream>>>(xth, asrc, adst, offs, bsum, csr, bias, out, N);
}